// Round 11
// baseline (750.967 us; speedup 1.0000x reference)
//
#include <hip/hip_runtime.h>
#include <stdint.h>

typedef __attribute__((ext_vector_type(8))) short short8;
typedef __attribute__((ext_vector_type(16))) float f32x16;
typedef __attribute__((ext_vector_type(4))) float f32x4;
typedef __attribute__((ext_vector_type(4))) unsigned short ushort4v;

union S8 { short8 v; unsigned short u[8]; };

static __device__ __forceinline__ unsigned short f2bf(float f) {
  union { float f; unsigned u; } v; v.f = f;
  unsigned r = v.u + 0x7fffu + ((v.u >> 16) & 1u);
  return (unsigned short)(r >> 16);
}

static __device__ __forceinline__ void glds16(const void* g, void* l) {
  __builtin_amdgcn_global_load_lds(
      (const __attribute__((address_space(1))) unsigned int*)g,
      (__attribute__((address_space(3))) unsigned int*)l, 16, 0, 0);
}

// ---------------- prep: W -> glds-ready per-(g8,kt) 16KB images ----------------
// t = ((((c*8+g8)*32+kt)*2+ks)*8+tt)*64+lane ; tt = s*4+gt4  (gt4 in 0..3)
// value = W_c[s][k = kt*32+ks*16+(lane>>5)*8+e][g = g8*128+gt4*32+(lane&31)]
__global__ __launch_bounds__(256) void prep_w(const float* __restrict__ Wa,
                                              const float* __restrict__ Wb,
                                              const float* __restrict__ Wc,
                                              unsigned short* __restrict__ wfrag) {
  int t    = blockIdx.x * 256 + threadIdx.x;
  int lane = t & 63;
  int tt   = (t >> 6) & 7;
  int ks   = (t >> 9) & 1;
  int kt   = (t >> 10) & 31;
  int g8   = (t >> 15) & 7;
  int c    = t >> 18;
  const float* W = (c == 0) ? Wa : (c == 1) ? Wb : Wc;
  int s  = tt >> 2, gt = tt & 3;
  int g  = g8*128 + gt*32 + (lane & 31);
  int k0 = kt*32 + ks*16 + ((lane >> 5) * 8);
  const float* src = W + (size_t)s * 1048576 + (size_t)k0 * 1024 + g;
  unsigned short* dst = wfrag + (size_t)t * 8;
#pragma unroll
  for (int e = 0; e < 8; ++e) dst[e] = f2bf(src[(size_t)e * 1024]);
}

// ---------------- prep: x -> A-fragment image for one channel ----------------
// t = (((gid*32+kt)*2+ks)*2+h)*64+lane ; value = A[row = h*32 + (lane&31)][k]
__global__ __launch_bounds__(256) void prep_x(const float* __restrict__ x,
                                              const int* __restrict__ idxp,
                                              int c, unsigned short* __restrict__ ximg) {
  int t = blockIdx.x * 256 + threadIdx.x;
  int lane = t & 63;
  int h  = (t >> 6) & 1;
  int ks = (t >> 7) & 1;
  int kt = (t >> 8) & 31;
  int gid = t >> 13;
  int b = gid >> 3, v = gid & 7;
  int vv = h ? idxp[v] : v;
  const float* src = x + (size_t)(b*8 + vv) * 32768;
  int i = lane & 31;
  int k0 = kt*32 + ks*16 + ((lane >> 5) * 8);
  S8 pk;
  if (c == 0) {
#pragma unroll
    for (int e = 0; e < 8; ++e) pk.u[e] = f2bf(src[(size_t)(k0 + e)*32 + i]);
  } else {
    const float* sp = (c == 1) ? (src + i*1024 + k0)
                               : (src + (k0 >> 5)*1024 + i*32 + (k0 & 31));
    float4 u0 = *(const float4*)sp, u1 = *(const float4*)(sp + 4);
    pk.u[0]=f2bf(u0.x); pk.u[1]=f2bf(u0.y); pk.u[2]=f2bf(u0.z); pk.u[3]=f2bf(u0.w);
    pk.u[4]=f2bf(u1.x); pk.u[5]=f2bf(u1.y); pk.u[6]=f2bf(u1.z); pk.u[7]=f2bf(u1.w);
  }
  *(short8*)(ximg + (size_t)t * 8) = pk.v;
}

// ---------------- prep: softmax A, Aoff frags, diag, BN affine ----------------
__global__ __launch_bounds__(256) void prep_misc(
    const float* e0, const int* a0, const float* b0, const float* g0, const float* be0, const float* rm0, const float* rv0,
    const float* e1, const int* a1, const float* b1, const float* g1, const float* be1, const float* rm1, const float* rv1,
    const float* e2, const int* a2, const float* b2, const float* g2, const float* be2, const float* rm2, const float* rv2,
    unsigned short* __restrict__ aofrag, float* __restrict__ diagA,
    float* __restrict__ scale2, float* __restrict__ shift2) {
  __shared__ float A[64][64];
  int c = blockIdx.x;
  int tid = threadIdx.x;
  const float* ev = (c==0)?e0:(c==1)?e1:e2;
  const int*   ad = (c==0)?a0:(c==1)?a1:a2;
  const float* bb = (c==0)?b0:(c==1)?b1:b2;
  const float* gm = (c==0)?g0:(c==1)?g1:g2;
  const float* bt = (c==0)?be0:(c==1)?be1:be2;
  const float* rm = (c==0)?rm0:(c==1)?rm1:rm2;
  const float* rv = (c==0)?rv0:(c==1)?rv1:rv2;
  if (tid < 64) {
    int n = tid;
    float mx = -3.0e38f;
    for (int m = 0; m < 64; ++m) {
      float lg = (ad[n*64+m] > 0) ? ev[n*64+m] : -9.0e15f;
      A[n][m] = lg; mx = fmaxf(mx, lg);
    }
    float ssum = 0.f;
    for (int m = 0; m < 64; ++m) { float p = __expf(A[n][m] - mx); A[n][m] = p; ssum += p; }
    float inv = 1.f / ssum;
    for (int m = 0; m < 64; ++m) A[n][m] *= inv;
  }
  __syncthreads();
  if (tid < 64) diagA[c*64 + tid] = A[tid][tid];
  for (int idx = tid; idx < 4096; idx += 256) {
    int e  = idx & 7;
    int l  = (idx >> 3) & 63;
    int ks = (idx >> 9) & 3;
    int nt = idx >> 11;
    int n = nt*32 + (l & 31);
    int m = ks*16 + ((l >> 5) * 8) + e;
    float vv = (m == n) ? 0.f : A[n][m];
    aofrag[c*4096 + idx] = f2bf(vv);
  }
  for (int g = tid; g < 1024; g += 256) {
    float sc = gm[g] * rsqrtf(rv[g] + 1e-5f);
    scale2[c*1024 + g] = sc;
    shift2[c*1024 + g] = bt[g] + (bb[g] - rm[g]) * sc;
  }
}

// ---------------- fallback A loader (IMG=0 only): f32 direct loads ----------------
template<int CH>
__device__ __forceinline__ void loadA(float av[2][8], const float* __restrict__ sview,
                                      int d0, int lh, int kt) {
#pragma unroll
  for (int ks = 0; ks < 2; ++ks) {
    int kb = kt*32 + ks*16 + lh*8;
    if (CH == 0) {
#pragma unroll
      for (int e = 0; e < 8; ++e) av[ks][e] = sview[(size_t)(kb + e)*32 + d0];
    } else if (CH == 1) {
      const float* sp = sview + d0*1024 + kb;
      *(float4*)&av[ks][0] = *(const float4*)sp;
      *(float4*)&av[ks][4] = *(const float4*)(sp + 4);
    } else {
      const float* sp = sview + kt*1024 + d0*32 + ks*16 + lh*8;
      *(float4*)&av[ks][0] = *(const float4*)sp;
      *(float4*)&av[ks][4] = *(const float4*)(sp + 4);
    }
  }
}

// ---------------- main fused channel kernel ----------------
// 512 threads / 8 waves; wave (wm = wave>>2, wn = wave&3): graph wm,
// weight-half s = wn>>1, col-subtile gsub = wn&1. Wave tile 64m x 64n, acc 64 regs.
// Block tile 128m x [128g x 2s]; BK=32; B tribuf 3x16KB glds 2-deep (vmcnt(2));
// A in regs from ximg (aE/aN parity sets, r9-verified schedule).
// 16 waves/CU target (4/SIMD) via __launch_bounds__(512,4).
// Epilogue: s=1 waves publish H1 (bf16, col-major swizzled, 32KB); s=0 waves
// fold agg = Aoff@H1 in-place into acc (their own H0) and write output.
template<int CH, int IMG>
__global__ __launch_bounds__(512, 4) void gconv(
    const float* __restrict__ x, const int* __restrict__ idxp,
    const unsigned short* __restrict__ wimg, const unsigned short* __restrict__ ximg,
    const unsigned short* __restrict__ aofrag,
    const float* __restrict__ diagA, const float* __restrict__ scale2,
    const float* __restrict__ shift2, float* __restrict__ out) {
  __shared__ alignas(128) char lds[49152];
  int tid = threadIdx.x, lane = tid & 63, wave = tid >> 6;
  int l31 = lane & 31, lh = lane >> 5;
  int wm = wave >> 2, wn = wave & 3;
  int s = wn >> 1, gsub = wn & 1;
  int bid = blockIdx.x;
  int g8 = bid & 7, mp = bid >> 3;
  int graphA = mp*2;
  int gid = graphA + wm;
  int b = gid >> 3, v = gid & 7;
  const float* v0 = x + (size_t)(b*8 + v) * 32768;          // IMG=0 only
  const float* v1 = x + (size_t)(b*8 + idxp[v]) * 32768;    // IMG=0 only

  const char* srcB  = (const char*)wimg + (size_t)g8 * 524288 + wave*2048 + lane*16;
  const char* srcAg = (const char*)ximg + (size_t)gid * 131072 + (size_t)lane*16;

  f32x16 acc[2][2];   // [mt][gt]
#pragma unroll
  for (int mt = 0; mt < 2; ++mt)
#pragma unroll
    for (int gt = 0; gt < 2; ++gt)
#pragma unroll
      for (int r = 0; r < 16; ++r) acc[mt][gt][r] = 0.f;

  char* pB0 = lds;  char* pB1 = lds + 16384;  char* pB2 = lds + 32768;
  int dW = wave * 2048;   // wave-uniform dest offset (glds adds lane*16)

  auto stageB = [&](char* dst, int kt) {      // 2 glds, wave stages 2 KB
    const char* sp = srcB + (size_t)kt * 16384;
    glds16(sp,        dst + dW);
    glds16(sp + 1024, dst + dW + 1024);
  };
  auto loadAreg = [&](short8 a[4], int kt) {
    if (IMG) {
      const char* sp = srcAg + (size_t)kt * 4096;
#pragma unroll
      for (int f = 0; f < 4; ++f) a[f] = *(const short8*)(sp + f*1024);  // f = ks*2+h
    } else {
#pragma unroll
      for (int h = 0; h < 2; ++h) {
        alignas(16) float av[2][8];
        loadA<CH>(av, h ? v1 : v0, l31, lh, kt);
#pragma unroll
        for (int ks = 0; ks < 2; ++ks) {
          S8 pk;
#pragma unroll
          for (int e = 0; e < 8; ++e) pk.u[e] = f2bf(av[ks][e]);
          a[ks*2 + h] = pk.v;
        }
      }
    }
  };
  auto compute = [&](const char* bB, const short8 a[4]) {   // 8 MFMA
    __builtin_amdgcn_s_setprio(1);
#pragma unroll
    for (int ks = 0; ks < 2; ++ks) {
      const char* bp = bB + ((ks*8 + s*4 + gsub*2)*64 + lane)*16;
#pragma unroll
      for (int gt = 0; gt < 2; ++gt) {
        short8 bf = *(const short8*)(bp + gt*1024);
        acc[0][gt] = __builtin_amdgcn_mfma_f32_32x32x16_bf16(a[ks*2    ], bf, acc[0][gt], 0, 0, 0);
        acc[1][gt] = __builtin_amdgcn_mfma_f32_32x32x16_bf16(a[ks*2 + 1], bf, acc[1][gt], 0, 0, 0);
      }
    }
    __builtin_amdgcn_s_setprio(0);
  };
  auto waitk = [&]() {
    if (IMG) asm volatile("s_waitcnt vmcnt(2)" ::: "memory");
    else     asm volatile("s_waitcnt vmcnt(0) lgkmcnt(0)" ::: "memory");
    __builtin_amdgcn_s_barrier();
  };

  short8 aE[4], aN[4];

  // ---- prologue: A(0)->aE; glds B(0); glds B(1). Issue order pinned. ----
  loadAreg(aE, 0);
  __builtin_amdgcn_sched_barrier(0);
  stageB(pB0, 0);
  __builtin_amdgcn_sched_barrier(0);
  stageB(pB1, 1);
  __builtin_amdgcn_sched_barrier(0);

#pragma unroll 1
  for (int kt = 0; kt < 30; kt += 2) {
    // even phase: queue = B(kt):2, A(kt):4, B(kt+1):2 -> vmcnt(2) retires B(kt)+A(kt)
    waitk();
    loadAreg(aN, kt + 1);
    __builtin_amdgcn_sched_barrier(0);
    stageB(pB2, kt + 2);
    __builtin_amdgcn_sched_barrier(0);
    compute(pB0, aE);
    { char* t = pB0; pB0 = pB1; pB1 = pB2; pB2 = t; }
    // odd phase: compute A(kt+1); load aE = A(kt+2) for the NEXT even phase
    waitk();
    loadAreg(aE, kt + 2);
    __builtin_amdgcn_sched_barrier(0);
    stageB(pB2, kt + 3);
    __builtin_amdgcn_sched_barrier(0);
    compute(pB0, aN);
    { char* t = pB0; pB0 = pB1; pB1 = pB2; pB2 = t; }
  }
  // phase 30: compute aE=A(30); load A(31); B(31) already staged
  waitk();
  loadAreg(aN, 31);
  __builtin_amdgcn_sched_barrier(0);
  compute(pB0, aE);
  { char* t = pB0; pB0 = pB1; pB1 = pB2; pB2 = t; }
  // phase 31
  asm volatile("s_waitcnt vmcnt(0) lgkmcnt(0)" ::: "memory");
  __builtin_amdgcn_s_barrier();
  compute(pB0, aN);
  __syncthreads();

  // ---- epilogue ----
  // s==1 waves: publish H1 (own 64 cols) bf16 col-major swizzled into lds[0,32K)
  if (s == 1) {
    char* basep = lds + wm*16384;
#pragma unroll
    for (int gt = 0; gt < 2; ++gt) {
      int col = gsub*64 + gt*32 + l31;
      char* cb = basep + col*128;
      int cs = (col & 7) << 4;
#pragma unroll
      for (int mt2 = 0; mt2 < 2; ++mt2)
#pragma unroll
        for (int j = 0; j < 4; ++j) {
          ushort4v pk;
          pk.x = f2bf(acc[mt2][gt][4*j+0]);
          pk.y = f2bf(acc[mt2][gt][4*j+1]);
          pk.z = f2bf(acc[mt2][gt][4*j+2]);
          pk.w = f2bf(acc[mt2][gt][4*j+3]);
          *(ushort4v*)(cb + ((mt2*64 + j*16 + lh*8) ^ cs)) = pk;
        }
    }
  }
  __syncthreads();

  // s==0 waves: agg = Aoff @ H1 folded in-place into acc (holds H0), then output
  if (s == 0) {
#pragma unroll
    for (int nta = 0; nta < 2; ++nta) {
      f32x16 agg[2];
#pragma unroll
      for (int gl = 0; gl < 2; ++gl)
#pragma unroll
        for (int r = 0; r < 16; ++r) agg[gl][r] = 0.f;
#pragma unroll
      for (int ks = 0; ks < 4; ++ks) {
        short8 aof = *(const short8*)((const char*)aofrag + (size_t)((nta*4 + ks)*64 + lane)*16);
#pragma unroll
        for (int gl = 0; gl < 2; ++gl) {
          int col = gsub*64 + gl*32 + l31;
          int cs = (col & 7) << 4;
          short8 hf = *(const short8*)(lds + wm*16384 + col*128 + ((ks*32 + lh*16) ^ cs));
          agg[gl] = __builtin_amdgcn_mfma_f32_32x32x16_bf16(aof, hf, agg[gl], 0, 0, 0);
        }
      }
      // fold: acc[nta] <- diag * acc[nta] + agg   (rows nta*32 + rowmap(q))
#pragma unroll
      for (int gl = 0; gl < 2; ++gl)
#pragma unroll
        for (int j = 0; j < 4; ++j)
#pragma unroll
          for (int jj = 0; jj < 4; ++jj) {
            int q = j*4 + jj;
            float d = diagA[nta*32 + j*8 + lh*4 + jj];
            acc[nta][gl][q] = d * acc[nta][gl][q] + agg[gl][q];
          }
    }
    // BN + ReLU + pair-mean + scatter
    size_t obase = (size_t)gid * 32768;
#pragma unroll
    for (int gl = 0; gl < 2; ++gl) {
      int g = g8*128 + gsub*64 + gl*32 + l31;
      float sc = scale2[g], sh = shift2[g];
#pragma unroll
      for (int j = 0; j < 4; ++j) {
        int i00 = j*8 + lh*4;
        float res[4];
#pragma unroll
        for (int jj = 0; jj < 4; ++jj) {
          int q = j*4 + jj;
          float va = fmaxf(acc[0][gl][q] * sc + sh, 0.f);
          float vb = fmaxf(acc[1][gl][q] * sc + sh, 0.f);
          res[jj] = 0.5f * (va + vb);
        }
        if (CH == 0) {
          float4 o4;
          o4.x = 0.5f*res[0]; o4.y = 0.5f*res[1]; o4.z = 0.5f*res[2]; o4.w = 0.5f*res[3];
          *(float4*)(out + obase + (size_t)g*32 + i00) = o4;
        } else if (CH == 1) {
#pragma unroll
          for (int jj = 0; jj < 4; ++jj)
            out[obase + (size_t)(i00 + jj)*1024 + g] += 0.25f * res[jj];
        } else {
#pragma unroll
          for (int jj = 0; jj < 4; ++jj)
            out[obase + (size_t)(g >> 5)*1024 + (size_t)(i00 + jj)*32 + (g & 31)] += 0.25f * res[jj];
        }
      }
    }
  }
}

extern "C" void kernel_launch(void* const* d_in, const int* in_sizes, int n_in,
                              void* d_out, int out_size, void* d_ws, size_t ws_size,
                              hipStream_t stream) {
  (void)in_sizes; (void)n_in; (void)out_size;
  const float* x    = (const float*)d_in[0];
  const int*   idx  = (const int*)d_in[1];
  const int*   adj1 = (const int*)d_in[2];
  const int*   adj2 = (const int*)d_in[3];
  const float *W[3], *e[3], *bb[3], *gm[3], *bt[3], *rm[3], *rv[3];
  for (int c = 0; c < 3; ++c) {
    int base = 4 + c*7;
    W[c]  = (const float*)d_in[base + 0];
    e[c]  = (const float*)d_in[base + 1];
    bb[c] = (const float*)d_in[base + 2];
    gm[c] = (const float*)d_in[base + 3];
    bt[c] = (const float*)d_in[base + 4];
    rm[c] = (const float*)d_in[base + 5];
    rv[c] = (const float*)d_in[base + 6];
  }
  char* ws = (char*)d_ws;
  unsigned short* wfrag  = (unsigned short*)ws;                    // 12 MB
  unsigned short* aofrag = (unsigned short*)(ws + 12582912);
  float* diagA  = (float*)(ws + 12607488);
  float* scale2 = (float*)(ws + 12608256);
  float* shift2 = (float*)(ws + 12620544);
  unsigned short* ximg = (unsigned short*)(ws + 16777216);         // 64 MB, reused per channel
  bool img = ws_size >= (size_t)(16777216 + 67108864);

  prep_w<<<3072, 256, 0, stream>>>(W[0], W[1], W[2], wfrag);
  prep_misc<<<3, 256, 0, stream>>>(
      e[0], adj1, bb[0], gm[0], bt[0], rm[0], rv[0],
      e[1], adj2, bb[1], gm[1], bt[1], rm[1], rv[1],
      e[2], adj2, bb[2], gm[2], bt[2], rm[2], rv[2],
      aofrag, diagA, scale2, shift2);

  float* out = (float*)d_out;
  if (img) {
    prep_x<<<16384, 256, 0, stream>>>(x, idx, 0, ximg);
    gconv<0,1><<<2048, 512, 0, stream>>>(x, idx, wfrag, ximg, aofrag,
                                         diagA, scale2, shift2, out);
    prep_x<<<16384, 256, 0, stream>>>(x, idx, 1, ximg);
    gconv<1,1><<<2048, 512, 0, stream>>>(x, idx, wfrag + 2097152, ximg, aofrag + 4096,
                                         diagA + 64,  scale2 + 1024, shift2 + 1024, out);
    prep_x<<<16384, 256, 0, stream>>>(x, idx, 2, ximg);
    gconv<2,1><<<2048, 512, 0, stream>>>(x, idx, wfrag + 4194304, ximg, aofrag + 8192,
                                         diagA + 128, scale2 + 2048, shift2 + 2048, out);
  } else {
    gconv<0,0><<<2048, 512, 0, stream>>>(x, idx, wfrag, ximg, aofrag,
                                         diagA, scale2, shift2, out);
    gconv<1,0><<<2048, 512, 0, stream>>>(x, idx, wfrag + 2097152, ximg, aofrag + 4096,
                                         diagA + 64,  scale2 + 1024, shift2 + 1024, out);
    gconv<2,0><<<2048, 512, 0, stream>>>(x, idx, wfrag + 4194304, ximg, aofrag + 8192,
                                         diagA + 128, scale2 + 2048, shift2 + 2048, out);
  }
}

// Round 12
// 362.395 us; speedup vs baseline: 2.0722x; 2.0722x over previous
//
#include <hip/hip_runtime.h>
#include <stdint.h>

typedef __attribute__((ext_vector_type(8))) short short8;
typedef __attribute__((ext_vector_type(16))) float f32x16;
typedef __attribute__((ext_vector_type(4))) unsigned short ushort4v;

union S8 { short8 v; unsigned short u[8]; };

static __device__ __forceinline__ unsigned short f2bf(float f) {
  union { float f; unsigned u; } v; v.f = f;
  unsigned r = v.u + 0x7fffu + ((v.u >> 16) & 1u);
  return (unsigned short)(r >> 16);
}
static __device__ __forceinline__ float bf2f(unsigned short u) {
  union { unsigned u; float f; } v; v.u = ((unsigned)u) << 16;
  return v.f;
}

static __device__ __forceinline__ void glds16(const void* g, void* l) {
  __builtin_amdgcn_global_load_lds(
      (const __attribute__((address_space(1))) unsigned int*)g,
      (__attribute__((address_space(3))) unsigned int*)l, 16, 0, 0);
}

// ---------------- prep: W -> glds-ready per-(g8,kt) 16KB images (unchanged) ----------------
// t = ((((c*8+g8)*32+kt)*2+ks)*8+tt)*64+lane ; tt = s*4+gt
// value = W_c[s][k = kt*32+ks*16+(lane>>5)*8+e][g = g8*128+gt*32+(lane&31)]
__global__ __launch_bounds__(256) void prep_w(const float* __restrict__ Wa,
                                              const float* __restrict__ Wb,
                                              const float* __restrict__ Wc,
                                              unsigned short* __restrict__ wfrag) {
  int t    = blockIdx.x * 256 + threadIdx.x;
  int lane = t & 63;
  int tt   = (t >> 6) & 7;
  int ks   = (t >> 9) & 1;
  int kt   = (t >> 10) & 31;
  int g8   = (t >> 15) & 7;
  int c    = t >> 18;
  const float* W = (c == 0) ? Wa : (c == 1) ? Wb : Wc;
  int s  = tt >> 2, gt = tt & 3;
  int g  = g8*128 + gt*32 + (lane & 31);
  int k0 = kt*32 + ks*16 + ((lane >> 5) * 8);
  const float* src = W + (size_t)s * 1048576 + (size_t)k0 * 1024 + g;
  unsigned short* dst = wfrag + (size_t)t * 8;
#pragma unroll
  for (int e = 0; e < 8; ++e) dst[e] = f2bf(src[(size_t)e * 1024]);
}

// ---------------- prep: x -> per-VIEW A-fragment image (dedup: no pair stack) ----------------
// t = ((vid*32+kt)*2+ks)*64+lane ; value = Xp_c[vid][row i = lane&31][k = kt*32+ks*16+(lane>>5)*8+e]
__global__ __launch_bounds__(256) void prep_x2(const float* __restrict__ x,
                                               int c, unsigned short* __restrict__ ximg) {
  int t = blockIdx.x * 256 + threadIdx.x;
  int lane = t & 63;
  int ks = (t >> 6) & 1;
  int kt = (t >> 7) & 31;
  int vid = t >> 12;
  const float* src = x + (size_t)vid * 32768;
  int i = lane & 31;
  int k0 = kt*32 + ks*16 + ((lane >> 5) * 8);
  S8 pk;
  if (c == 0) {
#pragma unroll
    for (int e = 0; e < 8; ++e) pk.u[e] = f2bf(src[(size_t)(k0 + e)*32 + i]);
  } else {
    const float* sp = (c == 1) ? (src + i*1024 + k0)
                               : (src + (k0 >> 5)*1024 + i*32 + (k0 & 31));
    float4 u0 = *(const float4*)sp, u1 = *(const float4*)(sp + 4);
    pk.u[0]=f2bf(u0.x); pk.u[1]=f2bf(u0.y); pk.u[2]=f2bf(u0.z); pk.u[3]=f2bf(u0.w);
    pk.u[4]=f2bf(u1.x); pk.u[5]=f2bf(u1.y); pk.u[6]=f2bf(u1.z); pk.u[7]=f2bf(u1.w);
  }
  *(short8*)(ximg + (size_t)t * 8) = pk.v;
}

// ---------------- prep: softmax A, Aoff frags, diag, BN affine (unchanged) ----------------
__global__ __launch_bounds__(256) void prep_misc(
    const float* e0, const int* a0, const float* b0, const float* g0, const float* be0, const float* rm0, const float* rv0,
    const float* e1, const int* a1, const float* b1, const float* g1, const float* be1, const float* rm1, const float* rv1,
    const float* e2, const int* a2, const float* b2, const float* g2, const float* be2, const float* rm2, const float* rv2,
    unsigned short* __restrict__ aofrag, float* __restrict__ diagA,
    float* __restrict__ scale2, float* __restrict__ shift2) {
  __shared__ float A[64][64];
  int c = blockIdx.x;
  int tid = threadIdx.x;
  const float* ev = (c==0)?e0:(c==1)?e1:e2;
  const int*   ad = (c==0)?a0:(c==1)?a1:a2;
  const float* bb = (c==0)?b0:(c==1)?b1:b2;
  const float* gm = (c==0)?g0:(c==1)?g1:g2;
  const float* bt = (c==0)?be0:(c==1)?be1:be2;
  const float* rm = (c==0)?rm0:(c==1)?rm1:rm2;
  const float* rv = (c==0)?rv0:(c==1)?rv1:rv2;
  if (tid < 64) {
    int n = tid;
    float mx = -3.0e38f;
    for (int m = 0; m < 64; ++m) {
      float lg = (ad[n*64+m] > 0) ? ev[n*64+m] : -9.0e15f;
      A[n][m] = lg; mx = fmaxf(mx, lg);
    }
    float ssum = 0.f;
    for (int m = 0; m < 64; ++m) { float p = __expf(A[n][m] - mx); A[n][m] = p; ssum += p; }
    float inv = 1.f / ssum;
    for (int m = 0; m < 64; ++m) A[n][m] *= inv;
  }
  __syncthreads();
  if (tid < 64) diagA[c*64 + tid] = A[tid][tid];
  for (int idx = tid; idx < 4096; idx += 256) {
    int e  = idx & 7;
    int l  = (idx >> 3) & 63;
    int ks = (idx >> 9) & 3;
    int nt = idx >> 11;
    int n = nt*32 + (l & 31);
    int m = ks*16 + ((l >> 5) * 8) + e;
    float vv = (m == n) ? 0.f : A[n][m];
    aofrag[c*4096 + idx] = f2bf(vv);
  }
  for (int g = tid; g < 1024; g += 256) {
    float sc = gm[g] * rsqrtf(rv[g] + 1e-5f);
    scale2[c*1024 + g] = sc;
    shift2[c*1024 + g] = bt[g] + (bb[g] - rm[g]) * sc;
  }
}

// ---------------- fallback A loader (IMG=0 only): f32 direct gather ----------------
template<int CH>
__device__ __forceinline__ void loadAfb(float av[2][8], const float* __restrict__ sview,
                                        int d0, int lh, int kt) {
#pragma unroll
  for (int ks = 0; ks < 2; ++ks) {
    int kb = kt*32 + ks*16 + lh*8;
    if (CH == 0) {
#pragma unroll
      for (int e = 0; e < 8; ++e) av[ks][e] = sview[(size_t)(kb + e)*32 + d0];
    } else if (CH == 1) {
      const float* sp = sview + d0*1024 + kb;
      *(float4*)&av[ks][0] = *(const float4*)sp;
      *(float4*)&av[ks][4] = *(const float4*)(sp + 4);
    } else {
      const float* sp = sview + kt*1024 + d0*32 + ks*16 + lh*8;
      *(float4*)&av[ks][0] = *(const float4*)sp;
      *(float4*)&av[ks][4] = *(const float4*)(sp + 4);
    }
  }
}

// ---------------- main fused channel kernel (dedup batch-block) ----------------
// Block = (batch b, g8): 256 rows (8 views x 32) x 128 g-cols x {H0,H1}.
// 512 thr / 8 waves: wave (wm = wave>>1, sn = wave&1): vids (2wm, 2wm+1), s = sn.
// Wave tile 64m x 128n, acc[2][4] (128 regs) — r9 per-wave intensity.
// Main loop = r9-verified even/odd counted-vmcnt pipeline (B glds 2/wave, vmcnt(2)).
// Epilogue: H1 (bf16 col-major swz) + H0 (bf16 C-layout) -> LDS; wave v combines
// graph (b,v): agg = Aoff @ [H1v;H1v2] (32 MFMA) + diag*H0 fold + BN + pair-mean.
template<int CH, int IMG>
__global__ __launch_bounds__(512, 2) void gconv(
    const float* __restrict__ x, const int* __restrict__ idxp,
    const unsigned short* __restrict__ wimg, const unsigned short* __restrict__ ximg,
    const unsigned short* __restrict__ aofrag,
    const float* __restrict__ diagA, const float* __restrict__ scale2,
    const float* __restrict__ shift2, float* __restrict__ out) {
  __shared__ alignas(128) char lds[131072];   // main: B tribuf [0,48K); epi: H1 [0,64K) + H0 [64K,128K)
  int tid = threadIdx.x, lane = tid & 63, wave = tid >> 6;
  int l31 = lane & 31, lh = lane >> 5;
  int wm = wave >> 1, sn = wave & 1;
  int bid = blockIdx.x;
  int g8 = bid & 7, b = bid >> 3;
  int v0l = 2*wm, v1l = v0l + 1;
  size_t vid0 = (size_t)b*8 + v0l, vid1 = vid0 + 1;
  const float* xv0 = x + vid0 * 32768;   // IMG=0 only
  const float* xv1 = x + vid1 * 32768;   // IMG=0 only

  const char* srcB  = (const char*)wimg + (size_t)g8 * 524288 + tid*16;   // tid*16 in [0,8K)
  const char* srcA0 = (const char*)ximg + vid0 * 65536 + lane*16;
  const char* srcA1 = (const char*)ximg + vid1 * 65536 + lane*16;

  f32x16 acc[2][4];
#pragma unroll
  for (int mt = 0; mt < 2; ++mt)
#pragma unroll
    for (int gt = 0; gt < 4; ++gt)
#pragma unroll
      for (int r = 0; r < 16; ++r) acc[mt][gt][r] = 0.f;

  char* pB0 = lds;  char* pB1 = lds + 16384;  char* pB2 = lds + 32768;
  int dW = wave * 1024;   // wave-uniform dest (glds adds lane*16); src tid*16 = wave*1024+lane*16

  auto stageB = [&](char* dst, int kt) {     // 2 glds/wave; 8 waves cover 16KB linearly
    const char* s = srcB + (size_t)kt * 16384;
    glds16(s,        dst + dW);
    glds16(s + 8192, dst + dW + 8192);
  };
  auto loadAreg = [&](short8 a[4], int kt) { // a[ks*2+mt]
    if (IMG) {
      const char* s0 = srcA0 + (size_t)kt * 2048;
      const char* s1 = srcA1 + (size_t)kt * 2048;
      a[0] = *(const short8*)s0;
      a[1] = *(const short8*)s1;
      a[2] = *(const short8*)(s0 + 1024);
      a[3] = *(const short8*)(s1 + 1024);
    } else {
#pragma unroll
      for (int h = 0; h < 2; ++h) {
        alignas(16) float av[2][8];
        loadAfb<CH>(av, h ? xv1 : xv0, l31, lh, kt);
#pragma unroll
        for (int ks = 0; ks < 2; ++ks) {
          S8 pk;
#pragma unroll
          for (int e = 0; e < 8; ++e) pk.u[e] = f2bf(av[ks][e]);
          a[ks*2 + h] = pk.v;
        }
      }
    }
  };
  auto compute = [&](const char* bB, const short8 a[4]) {   // 16 MFMA
    __builtin_amdgcn_s_setprio(1);
#pragma unroll
    for (int ks = 0; ks < 2; ++ks) {
      const char* bp = bB + ((ks*8 + sn*4)*64 + lane)*16;
#pragma unroll
      for (int gt = 0; gt < 4; ++gt) {
        short8 bf = *(const short8*)(bp + gt*1024);
        acc[0][gt] = __builtin_amdgcn_mfma_f32_32x32x16_bf16(a[ks*2    ], bf, acc[0][gt], 0, 0, 0);
        acc[1][gt] = __builtin_amdgcn_mfma_f32_32x32x16_bf16(a[ks*2 + 1], bf, acc[1][gt], 0, 0, 0);
      }
    }
    __builtin_amdgcn_s_setprio(0);
  };
  auto waitk = [&]() {
    if (IMG) asm volatile("s_waitcnt vmcnt(2)" ::: "memory");
    else     asm volatile("s_waitcnt vmcnt(0) lgkmcnt(0)" ::: "memory");
    __builtin_amdgcn_s_barrier();
  };

  short8 aE[4], aN[4];

  // ---- prologue (r9-verified shape): A(0)->aE; glds B(0); glds B(1) ----
  loadAreg(aE, 0);
  __builtin_amdgcn_sched_barrier(0);
  stageB(pB0, 0);
  __builtin_amdgcn_sched_barrier(0);
  stageB(pB1, 1);
  __builtin_amdgcn_sched_barrier(0);

#pragma unroll 1
  for (int kt = 0; kt < 30; kt += 2) {
    // even: queue A(kt):4?,B(kt):2,B(kt+1):2 -> vmcnt(2) retires all but B(kt+1)
    waitk();
    loadAreg(aN, kt + 1);
    __builtin_amdgcn_sched_barrier(0);
    stageB(pB2, kt + 2);
    __builtin_amdgcn_sched_barrier(0);
    compute(pB0, aE);
    { char* t = pB0; pB0 = pB1; pB1 = pB2; pB2 = t; }
    // odd: compute A(kt+1); load aE = A(kt+2)
    waitk();
    loadAreg(aE, kt + 2);
    __builtin_amdgcn_sched_barrier(0);
    stageB(pB2, kt + 3);
    __builtin_amdgcn_sched_barrier(0);
    compute(pB0, aN);
    { char* t = pB0; pB0 = pB1; pB1 = pB2; pB2 = t; }
  }
  // phase 30
  waitk();
  loadAreg(aN, 31);
  __builtin_amdgcn_sched_barrier(0);
  compute(pB0, aE);
  { char* t = pB0; pB0 = pB1; pB1 = pB2; pB2 = t; }
  // phase 31
  asm volatile("s_waitcnt vmcnt(0) lgkmcnt(0)" ::: "memory");
  __builtin_amdgcn_s_barrier();
  compute(pB0, aN);
  __syncthreads();

  // ---- epilogue: publish H to LDS ----
  char* H1r = lds;            // [v(8)][col(128)][64B col-major rows, 16B-XOR swz]
  char* H0r = lds + 65536;    // [v(8)][gt(4)][rh(2)][lane(64)][16B] C-layout bf16
  if (sn == 1) {
#pragma unroll
    for (int mt = 0; mt < 2; ++mt) {
      int vloc = v0l + mt;
#pragma unroll
      for (int gt = 0; gt < 4; ++gt) {
        int col = gt*32 + l31;
        int xw = (col & 3) << 4;
        char* cb = H1r + vloc*8192 + col*64;
#pragma unroll
        for (int j = 0; j < 4; ++j) {
          ushort4v pk;
          pk.x = f2bf(acc[mt][gt][4*j+0]);
          pk.y = f2bf(acc[mt][gt][4*j+1]);
          pk.z = f2bf(acc[mt][gt][4*j+2]);
          pk.w = f2bf(acc[mt][gt][4*j+3]);
          *(ushort4v*)(cb + ((j*16 + lh*8) ^ xw)) = pk;
        }
      }
    }
  } else {
#pragma unroll
    for (int mt = 0; mt < 2; ++mt) {
      int vloc = v0l + mt;
#pragma unroll
      for (int gt = 0; gt < 4; ++gt) {
        char* cb = H0r + vloc*8192 + gt*2048 + lane*16;
        S8 lo, hi;
#pragma unroll
        for (int e = 0; e < 8; ++e) { lo.u[e] = f2bf(acc[mt][gt][e]); hi.u[e] = f2bf(acc[mt][gt][8+e]); }
        *(short8*)cb = lo.v;
        *(short8*)(cb + 1024) = hi.v;
      }
    }
  }
  __syncthreads();

  // ---- combine: wave v handles graph (b, v) ----
  {
    int v = wave;
    int v2 = idxp[v];
    f32x16 agg[2][4];
#pragma unroll
    for (int nt = 0; nt < 2; ++nt)
#pragma unroll
      for (int gt = 0; gt < 4; ++gt)
#pragma unroll
        for (int r = 0; r < 16; ++r) agg[nt][gt][r] = 0.f;

#pragma unroll
    for (int ks = 0; ks < 4; ++ks) {
      int vsel = (ks < 2) ? v : v2;
      int ksl = ks & 1;
      short8 aof0 = *(const short8*)((const char*)aofrag + (size_t)((0*4 + ks)*64 + lane)*16);
      short8 aof1 = *(const short8*)((const char*)aofrag + (size_t)((1*4 + ks)*64 + lane)*16);
#pragma unroll
      for (int gt = 0; gt < 4; ++gt) {
        int col = gt*32 + l31;
        int xw = (col & 3) << 4;
        short8 hf = *(const short8*)(H1r + vsel*8192 + col*64 + ((ksl*32 + lh*16) ^ xw));
        agg[0][gt] = __builtin_amdgcn_mfma_f32_32x32x16_bf16(aof0, hf, agg[0][gt], 0, 0, 0);
        agg[1][gt] = __builtin_amdgcn_mfma_f32_32x32x16_bf16(aof1, hf, agg[1][gt], 0, 0, 0);
      }
    }

    size_t gid = (size_t)b*8 + v;
    size_t obase = gid * 32768;
#pragma unroll
    for (int gt = 0; gt < 4; ++gt) {
      int g = g8*128 + gt*32 + l31;
      float sc = scale2[g], sh = shift2[g];
      S8 h0a0, h0a1, h0b0, h0b1;
      h0a0.v = *(const short8*)(H0r + v *8192 + gt*2048 + lane*16);
      h0a1.v = *(const short8*)(H0r + v *8192 + gt*2048 + 1024 + lane*16);
      h0b0.v = *(const short8*)(H0r + v2*8192 + gt*2048 + lane*16);
      h0b1.v = *(const short8*)(H0r + v2*8192 + gt*2048 + 1024 + lane*16);
#pragma unroll
      for (int j = 0; j < 4; ++j) {
        int i00 = j*8 + lh*4;
        float res[4];
#pragma unroll
        for (int jj = 0; jj < 4; ++jj) {
          int q = j*4 + jj;
          int i = i00 + jj;
          float h0v  = (q < 8) ? bf2f(h0a0.u[q]) : bf2f(h0a1.u[q-8]);
          float h0v2 = (q < 8) ? bf2f(h0b0.u[q]) : bf2f(h0b1.u[q-8]);
          float va = diagA[i]      * h0v  + agg[0][gt][q];
          float vb = diagA[32 + i] * h0v2 + agg[1][gt][q];
          va = fmaxf(va * sc + sh, 0.f);
          vb = fmaxf(vb * sc + sh, 0.f);
          res[jj] = 0.5f * (va + vb);
        }
        if (CH == 0) {
          float4 o4;
          o4.x = 0.5f*res[0]; o4.y = 0.5f*res[1]; o4.z = 0.5f*res[2]; o4.w = 0.5f*res[3];
          *(float4*)(out + obase + (size_t)g*32 + i00) = o4;
        } else if (CH == 1) {
#pragma unroll
          for (int jj = 0; jj < 4; ++jj)
            out[obase + (size_t)(i00 + jj)*1024 + g] += 0.25f * res[jj];
        } else {
#pragma unroll
          for (int jj = 0; jj < 4; ++jj)
            out[obase + (size_t)(g >> 5)*1024 + (size_t)(i00 + jj)*32 + (g & 31)] += 0.25f * res[jj];
        }
      }
    }
  }
}

extern "C" void kernel_launch(void* const* d_in, const int* in_sizes, int n_in,
                              void* d_out, int out_size, void* d_ws, size_t ws_size,
                              hipStream_t stream) {
  (void)in_sizes; (void)n_in; (void)out_size;
  const float* x    = (const float*)d_in[0];
  const int*   idx  = (const int*)d_in[1];
  const int*   adj1 = (const int*)d_in[2];
  const int*   adj2 = (const int*)d_in[3];
  const float *W[3], *e[3], *bb[3], *gm[3], *bt[3], *rm[3], *rv[3];
  for (int c = 0; c < 3; ++c) {
    int base = 4 + c*7;
    W[c]  = (const float*)d_in[base + 0];
    e[c]  = (const float*)d_in[base + 1];
    bb[c] = (const float*)d_in[base + 2];
    gm[c] = (const float*)d_in[base + 3];
    bt[c] = (const float*)d_in[base + 4];
    rm[c] = (const float*)d_in[base + 5];
    rv[c] = (const float*)d_in[base + 6];
  }
  char* ws = (char*)d_ws;
  unsigned short* wfrag  = (unsigned short*)ws;                    // 12 MB
  unsigned short* aofrag = (unsigned short*)(ws + 12582912);
  float* diagA  = (float*)(ws + 12607488);
  float* scale2 = (float*)(ws + 12608256);
  float* shift2 = (float*)(ws + 12620544);
  unsigned short* ximg = (unsigned short*)(ws + 16777216);         // 32 MB, reused per channel
  bool img = ws_size >= (size_t)(16777216 + 33554432);

  prep_w<<<3072, 256, 0, stream>>>(W[0], W[1], W[2], wfrag);
  prep_misc<<<3, 256, 0, stream>>>(
      e[0], adj1, bb[0], gm[0], bt[0], rm[0], rv[0],
      e[1], adj2, bb[1], gm[1], bt[1], rm[1], rv[1],
      e[2], adj2, bb[2], gm[2], bt[2], rm[2], rv[2],
      aofrag, diagA, scale2, shift2);

  float* out = (float*)d_out;
  if (img) {
    prep_x2<<<8192, 256, 0, stream>>>(x, 0, ximg);
    gconv<0,1><<<512, 512, 0, stream>>>(x, idx, wfrag, ximg, aofrag,
                                        diagA, scale2, shift2, out);
    prep_x2<<<8192, 256, 0, stream>>>(x, 1, ximg);
    gconv<1,1><<<512, 512, 0, stream>>>(x, idx, wfrag + 2097152, ximg, aofrag + 4096,
                                        diagA + 64,  scale2 + 1024, shift2 + 1024, out);
    prep_x2<<<8192, 256, 0, stream>>>(x, 2, ximg);
    gconv<2,1><<<512, 512, 0, stream>>>(x, idx, wfrag + 4194304, ximg, aofrag + 8192,
                                        diagA + 128, scale2 + 2048, shift2 + 2048, out);
  } else {
    gconv<0,0><<<512, 512, 0, stream>>>(x, idx, wfrag, ximg, aofrag,
                                        diagA, scale2, shift2, out);
    gconv<1,0><<<512, 512, 0, stream>>>(x, idx, wfrag + 2097152, ximg, aofrag + 4096,
                                        diagA + 64,  scale2 + 1024, shift2 + 1024, out);
    gconv<2,0><<<512, 512, 0, stream>>>(x, idx, wfrag + 4194304, ximg, aofrag + 8192,
                                        diagA + 128, scale2 + 2048, shift2 + 2048, out);
  }
}